// Round 1
// baseline (46.586 us; speedup 1.0000x reference)
//
#include <hip/hip_runtime.h>

// op 0: fmod(a,b) * W_mod ; op 1: gcd(int(a),int(b)) * W_gcd ; else 0.
// a,b are integer-valued floats in [1, 1e6) -> exact in fp32 (< 2^24).
// Euclid step done entirely in fp32: q = floor(x * rcp(y)), r = fma(-q,y,x),
// with two one-ulp fixups (q can be off by at most 1 since x < 2^20 and
// v_rcp_f32 has <= 1 ulp error -> |x*rcp(y) - x/y| < 0.25).

__device__ __forceinline__ float euclid_step(float x, float y) {
    // precondition: y >= 1, x >= 0, both integer-valued, < 2^24
    float q = floorf(x * __builtin_amdgcn_rcpf(y));
    float r = fmaf(-q, y, x);          // exact: |q*y| ~ x < 2^24
    r = (r < 0.0f)  ? r + y : r;       // q was 1 too high
    r = (r >= y)    ? r - y : r;       // q was 1 too low
    return r;
}

__device__ __forceinline__ float elem_compute(float a, float b, int op,
                                              float wm, float wg) {
    float r0 = euclid_step(a, b);      // = a mod b (exact integer)
    if (op == 0) return r0 * wm;
    if (op != 1) return 0.0f;
    // gcd: continue Euclid from (b, a mod b)
    float x = b, y = r0;
    while (y > 0.0f) {
        float r = euclid_step(x, y);
        x = y;
        y = r;
    }
    return x * wg;
}

extern "C" __global__ void __launch_bounds__(256)
nt_kernel(const float4* __restrict__ a4, const float4* __restrict__ b4,
          const int4* __restrict__ op4, const float* __restrict__ Wm,
          const float* __restrict__ Wg, float4* __restrict__ out4, int n4)
{
    const float wm = Wm[0];
    const float wg = Wg[0];
    const int stride = gridDim.x * blockDim.x;
    for (int i = blockIdx.x * blockDim.x + threadIdx.x; i < n4; i += stride) {
        const float4 a = a4[i];
        const float4 b = b4[i];
        const int4  op = op4[i];
        float4 o;
        o.x = elem_compute(a.x, b.x, op.x, wm, wg);
        o.y = elem_compute(a.y, b.y, op.y, wm, wg);
        o.z = elem_compute(a.z, b.z, op.z, wm, wg);
        o.w = elem_compute(a.w, b.w, op.w, wm, wg);
        out4[i] = o;
    }
}

extern "C" void kernel_launch(void* const* d_in, const int* in_sizes, int n_in,
                              void* d_out, int out_size, void* d_ws, size_t ws_size,
                              hipStream_t stream) {
    const float* a   = (const float*)d_in[0];
    const float* b   = (const float*)d_in[1];
    const int*   op  = (const int*)d_in[2];
    const float* Wm  = (const float*)d_in[3];
    const float* Wg  = (const float*)d_in[4];
    float* out = (float*)d_out;

    const int n  = in_sizes[0];      // 8388608
    const int n4 = n >> 2;           // 2097152 float4 elements
    const int threads = 256;
    const int blocks  = (n4 + threads - 1) / threads;   // 8192

    nt_kernel<<<blocks, threads, 0, stream>>>(
        (const float4*)a, (const float4*)b, (const int4*)op, Wm, Wg,
        (float4*)out, n4);
}

// Round 2
// 32.826 us; speedup vs baseline: 1.4192x; 1.4192x over previous
//
#include <hip/hip_runtime.h>

// op 0: fmod(a,b) * W_mod ; op 1: gcd(int(a),int(b)) * W_gcd ; else 0.
// a,b integer-valued floats in [1, 1e6) -> exact in fp32.
//
// One-fixup Euclid step: q = floor(fma(x, rcp(y), -0.5)).
//   |x*rcp(y) - x/y| <= x/y * 2^-23 (rcp <=1ulp) + ulp/2 of fma <= 0.125+0.0625
//   so q_hat = x/y - 0.5 +/- 0.19 -> floor(q_hat) in {k-1, k} where k = floor(x/y).
//   r = fma(-q, y, x) is an exact integer in [0, 2y); one conditional subtract fixes it.
//
// Structure: phase A computes a mod b for every element (= Euclid step 1),
// writes mod results to an LDS result array, and compacts gcd tasks into an
// LDS queue (ballot + popc prefix, one LDS atomic per wave per component).
// Phase B runs the queued gcd loops with all 64 lanes dense. Phase C does one
// coalesced float4 store per thread.

#define TPB 256
#define EPB 1024   // elements per block = TPB * 4

__device__ __forceinline__ float euclid_step(float x, float y) {
    // precondition: y >= 1, x >= 0, both integer-valued, < 2^20
    float q = floorf(fmaf(x, __builtin_amdgcn_rcpf(y), -0.5f));
    float r = fmaf(-q, y, x);          // exact integer in [0, 2y)
    return (r >= y) ? r - y : r;
}

extern "C" __global__ void __launch_bounds__(256)
nt_kernel(const float4* __restrict__ a4, const float4* __restrict__ b4,
          const int4* __restrict__ op4, const float* __restrict__ Wm,
          const float* __restrict__ Wg, float4* __restrict__ out4, int n4)
{
    __shared__ __align__(16) float res[EPB];
    __shared__ float qx[EPB];
    __shared__ float qy[EPB];
    __shared__ int   qslot[EPB];
    __shared__ int   cnt;

    const int tid = threadIdx.x;
    if (tid == 0) cnt = 0;
    __syncthreads();

    const float wm = Wm[0];
    const float wg = Wg[0];
    const int i = blockIdx.x * TPB + tid;       // float4 index
    const unsigned lane = tid & 63u;
    const bool valid = (i < n4);

    // ---- phase A: mod for everyone, queue gcd tasks ----
    if (valid) {
        const float4 a = a4[i];
        const float4 b = b4[i];
        const int4  op = op4[i];
        #pragma unroll
        for (int j = 0; j < 4; ++j) {
            const float aj = (&a.x)[j];
            const float bj = (&b.x)[j];
            const int  opj = (&op.x)[j];
            const float r0 = euclid_step(aj, bj);       // a mod b, exact
            res[tid * 4 + j] = (opj == 0) ? r0 * wm : 0.0f;
            const bool need = (opj == 1);
            const unsigned long long mask = __ballot(need);
            const int total = __popcll(mask);
            int base = 0;
            if (lane == 0 && total) base = atomicAdd(&cnt, total);
            base = __shfl(base, 0);
            if (need) {
                const int pos = base + __popcll(mask & ((1ull << lane) - 1ull));
                qx[pos] = bj;          // continue Euclid from (b, a mod b)
                qy[pos] = r0;
                qslot[pos] = tid * 4 + j;
            }
        }
    }
    __syncthreads();

    // ---- phase B: dense gcd over the queue ----
    const int total = cnt;
    for (int idx = tid; idx < total; idx += TPB) {
        float x = qx[idx];
        float y = qy[idx];
        while (y > 0.0f) {
            const float r = euclid_step(x, y);
            x = y;
            y = r;
        }
        res[qslot[idx]] = x * wg;
    }
    __syncthreads();

    // ---- phase C: coalesced write-out ----
    if (valid) {
        out4[i] = ((const float4*)res)[tid];
    }
}

extern "C" void kernel_launch(void* const* d_in, const int* in_sizes, int n_in,
                              void* d_out, int out_size, void* d_ws, size_t ws_size,
                              hipStream_t stream) {
    const float* a   = (const float*)d_in[0];
    const float* b   = (const float*)d_in[1];
    const int*   op  = (const int*)d_in[2];
    const float* Wm  = (const float*)d_in[3];
    const float* Wg  = (const float*)d_in[4];
    float* out = (float*)d_out;

    const int n  = in_sizes[0];      // 8388608
    const int n4 = n >> 2;           // 2097152 float4 elements
    const int blocks = (n4 + TPB - 1) / TPB;   // 8192

    nt_kernel<<<blocks, TPB, 0, stream>>>(
        (const float4*)a, (const float4*)b, (const int4*)op, Wm, Wg,
        (float4*)out, n4);
}

// Round 3
// 29.585 us; speedup vs baseline: 1.5747x; 1.1095x over previous
//
#include <hip/hip_runtime.h>

// op 0: fmod(a,b) * W_mod ; op 1: gcd(int(a),int(b)) * W_gcd ; else 0.
// a,b integer-valued floats in [1, 1e6) -> exact in fp32.
//
// mod step (proven round 1): q = floor(fma(x, rcp(y), -0.5)) is within +/-0.19
// of x/y - 0.5, so q in {k-1, k}; r = fma(-q, y, x) is an exact integer in
// [0, 2y); one conditional subtract gives the exact mod.
//
// gcd uses CENTERED remainders: after r = x mod y, continue with
// r' = min(r, y - r). gcd(y, r') == gcd(y, r) since r' == +/-r (mod y), and
// y at least halves every step -> <= ~20 steps for y < 2^20, avg ~8.
// This compresses the per-wave max iteration count (the real cost).
//
// Structure: each WAVE owns 256 elements (4 per lane). It compacts its gcd
// tasks into a wave-private LDS queue via ballot + mbcnt prefix + SGPR
// running count -> no atomics, no __syncthreads anywhere (same-wave LDS
// ordering is guaranteed by the in-order DS pipeline).

#define TPB 256

__device__ __forceinline__ float mod_step(float x, float y) {
    // precondition: y >= 1, x >= 0, both integer-valued, < 2^24
    float q = floorf(fmaf(x, __builtin_amdgcn_rcpf(y), -0.5f));
    float r = fmaf(-q, y, x);          // exact integer in [0, 2y)
    return (r >= y) ? r - y : r;
}

extern "C" __global__ void __launch_bounds__(256)
nt_kernel(const float4* __restrict__ a4, const float4* __restrict__ b4,
          const int4* __restrict__ op4, const float* __restrict__ Wm,
          const float* __restrict__ Wg, float4* __restrict__ out4, int n4)
{
    __shared__ __align__(16) float res[1024];   // per-block results, 4/thread
    __shared__ float qb[1024];                  // queue: x0 = b
    __shared__ float qr[1024];                  // queue: y0 = a mod b
    __shared__ int   qs[1024];                  // queue: result slot

    const int tid   = threadIdx.x;
    const int lane  = tid & 63;
    const int wbase = (tid >> 6) << 8;          // 256 queue slots per wave

    const int i = blockIdx.x * TPB + tid;       // float4 index
    const bool valid = (i < n4);
    const float wm = Wm[0];
    const float wg = Wg[0];

    // ---- phase A: mod for everyone, wave-local gcd-task compaction ----
    int qcount = 0;
    if (valid) {
        const float4 a = a4[i];
        const float4 b = b4[i];
        const int4  op = op4[i];
        #pragma unroll
        for (int j = 0; j < 4; ++j) {
            const float aj = (&a.x)[j];
            const float bj = (&b.x)[j];
            const int  opj = (&op.x)[j];
            const float r0 = mod_step(aj, bj);        // a mod b, exact
            res[tid * 4 + j] = (opj == 0) ? r0 * wm : 0.0f;
            const bool need = (opj == 1);
            const unsigned long long mask = __ballot(need);
            if (need) {
                const int pos = wbase + qcount +
                    (int)__popcll(mask & ((1ull << lane) - 1ull));
                qb[pos] = bj;
                qr[pos] = r0;
                qs[pos] = tid * 4 + j;
            }
            qcount += (int)__popcll(mask);            // wave-uniform (SGPR)
        }
    }

    // ---- phase B: dense centered-Euclid over the wave's own queue ----
    // (no barrier: producer and consumer are the same wave)
    for (int k = lane; k < qcount; k += 64) {
        float x = qb[wbase + k];
        float y = qr[wbase + k];
        const int slot = qs[wbase + k];
        while (y > 0.0f) {
            float r = mod_step(x, y);
            r = fminf(r, y - r);       // centered remainder: <= y/2
            x = y;
            y = r;
        }
        res[slot] = x * wg;
    }

    // ---- phase C: coalesced write-out (own wave's region only) ----
    if (valid) {
        out4[i] = ((const float4*)res)[tid];
    }
}

extern "C" void kernel_launch(void* const* d_in, const int* in_sizes, int n_in,
                              void* d_out, int out_size, void* d_ws, size_t ws_size,
                              hipStream_t stream) {
    const float* a   = (const float*)d_in[0];
    const float* b   = (const float*)d_in[1];
    const int*   op  = (const int*)d_in[2];
    const float* Wm  = (const float*)d_in[3];
    const float* Wg  = (const float*)d_in[4];
    float* out = (float*)d_out;

    const int n  = in_sizes[0];      // 8388608
    const int n4 = n >> 2;           // 2097152 float4 elements
    const int blocks = (n4 + TPB - 1) / TPB;   // 8192

    nt_kernel<<<blocks, TPB, 0, stream>>>(
        (const float4*)a, (const float4*)b, (const int4*)op, Wm, Wg,
        (float4*)out, n4);
}